// Round 13
// baseline (323.773 us; speedup 1.0000x reference)
//
#include <hip/hip_runtime.h>
#include <hip/hip_bf16.h>
#include <math.h>

#define FIN 512
#define NHID 32
#define LAT 16
#define BCAP 16384  // records per 256-node bucket (mean 8192, sigma ~90)

// ---------------------------------------------------------------------------
// GEMM1: [n,512] @ [512,32] -> [n,32]. K-split x2 (round-10 form: best
// measured). XOR-swizzled xT. Partials -> out0/out1, add2 merges.
// ---------------------------------------------------------------------------
#define BR 128
#define KC 64
__global__ __launch_bounds__(256) void gemm_fin(const float* __restrict__ feat,
                                                const float* __restrict__ W,
                                                float* __restrict__ out0,
                                                float* __restrict__ out1,
                                                int n, int ntile) {
    __shared__ float xT[KC][BR];    // 32 KB, swizzled
    __shared__ float Wc[KC][NHID];  // 8 KB
    const int tid = threadIdx.x;
    const int tile = blockIdx.x % ntile;
    const int khalf = blockIdx.x / ntile;
    const int r0 = tile * BR;
    const int k0 = khalf * 256;
    float* __restrict__ out = khalf ? out1 : out0;
    const int rt = tid >> 3;
    const int ct = tid & 7;
    const int srow = tid >> 4;
    const int sc4 = tid & 15;
    float acc[4][4] = {{0.f}};

    for (int kc = 0; kc < 256; kc += KC) {
        {
            const float4* wg = reinterpret_cast<const float4*>(W + (k0 + kc) * NHID);
            float4* wl = reinterpret_cast<float4*>(&Wc[0][0]);
            wl[tid] = wg[tid];
            wl[tid + 256] = wg[tid + 256];
        }
#pragma unroll
        for (int i = 0; i < 8; ++i) {
            int rr = srow + 16 * i;
            int r = r0 + rr;
            float4 v;
            if (r < n)
                v = *reinterpret_cast<const float4*>(feat + (size_t)r * FIN + k0 + kc + sc4 * 4);
            else
                v.x = v.y = v.z = v.w = 0.f;
            int gs = ((rr >> 2) ^ (sc4 & 7)) * 4 + (rr & 3);
            xT[sc4 * 4 + 0][gs] = v.x;
            xT[sc4 * 4 + 1][gs] = v.y;
            xT[sc4 * 4 + 2][gs] = v.z;
            xT[sc4 * 4 + 3][gs] = v.w;
        }
        __syncthreads();
#pragma unroll 4
        for (int k = 0; k < KC; ++k) {
            int sw = (rt ^ ((k >> 2) & 7)) * 4;
            float4 xv = *reinterpret_cast<const float4*>(&xT[k][sw]);
            float4 wv = *reinterpret_cast<const float4*>(&Wc[k][ct * 4]);
            acc[0][0] = fmaf(xv.x, wv.x, acc[0][0]);
            acc[0][1] = fmaf(xv.x, wv.y, acc[0][1]);
            acc[0][2] = fmaf(xv.x, wv.z, acc[0][2]);
            acc[0][3] = fmaf(xv.x, wv.w, acc[0][3]);
            acc[1][0] = fmaf(xv.y, wv.x, acc[1][0]);
            acc[1][1] = fmaf(xv.y, wv.y, acc[1][1]);
            acc[1][2] = fmaf(xv.y, wv.z, acc[1][2]);
            acc[1][3] = fmaf(xv.y, wv.w, acc[1][3]);
            acc[2][0] = fmaf(xv.z, wv.x, acc[2][0]);
            acc[2][1] = fmaf(xv.z, wv.y, acc[2][1]);
            acc[2][2] = fmaf(xv.z, wv.z, acc[2][2]);
            acc[2][3] = fmaf(xv.z, wv.w, acc[2][3]);
            acc[3][0] = fmaf(xv.w, wv.x, acc[3][0]);
            acc[3][1] = fmaf(xv.w, wv.y, acc[3][1]);
            acc[3][2] = fmaf(xv.w, wv.z, acc[3][2]);
            acc[3][3] = fmaf(xv.w, wv.w, acc[3][3]);
        }
        __syncthreads();
    }
#pragma unroll
    for (int i = 0; i < 4; ++i) {
        int r = r0 + rt * 4 + i;
        if (r < n) {
            float4 o;
            o.x = acc[i][0]; o.y = acc[i][1]; o.z = acc[i][2]; o.w = acc[i][3];
            *reinterpret_cast<float4*>(out + (size_t)r * NHID + ct * 4) = o;
        }
    }
}

// a += b (float4), for the K-split reduction.
__global__ __launch_bounds__(256) void add2(float* __restrict__ a,
                                            const float* __restrict__ b, int n4) {
    int i = blockIdx.x * 256 + threadIdx.x;
    if (i < n4) {
        float4 va = reinterpret_cast<float4*>(a)[i];
        float4 vb = reinterpret_cast<const float4*>(b)[i];
        va.x += vb.x; va.y += vb.y; va.z += vb.z; va.w += vb.w;
        reinterpret_cast<float4*>(a)[i] = va;
    }
}

// ---------------------------------------------------------------------------
// CSR build, fixed-capacity buckets (round-10 form: simple scatter, tiny LDS,
// high occupancy — the round-11 LDS counting-sort cost 2 blocks/CU and lost).
// ---------------------------------------------------------------------------
__global__ __launch_bounds__(256) void binit(int* __restrict__ bcursor, int nb) {
    int t = threadIdx.x;
    if (t < nb) bcursor[t] = t * BCAP;
}

__global__ __launch_bounds__(256) void build_a(const int* __restrict__ src,
                                               const int* __restrict__ dst,
                                               const float* __restrict__ w,
                                               int* __restrict__ bcursor,
                                               unsigned long long* __restrict__ rec2,
                                               int e, int nb) {
    __shared__ int cnt[256];
    __shared__ int gb[256];
    const int tid = threadIdx.x;
    const int i0 = blockIdx.x * 4096;
    cnt[tid] = 0;
    __syncthreads();
    unsigned long long rc[16];
    int rkbk[16];
#pragma unroll
    for (int k = 0; k < 16; ++k) {
        int j = i0 + k * 256 + tid;
        rkbk[k] = -1;
        if (j < e) {
            int d = dst[j];
            int b = d >> 8;
            int rk = atomicAdd(&cnt[b], 1);
            rkbk[k] = (rk << 8) | b;
            rc[k] = ((unsigned long long)__float_as_uint(w[j]) << 32) |
                    ((unsigned)d << 16) | (unsigned)src[j];
        }
    }
    __syncthreads();
    if (tid < nb && cnt[tid] > 0) gb[tid] = atomicAdd(&bcursor[tid], cnt[tid]);
    __syncthreads();
#pragma unroll
    for (int k = 0; k < 16; ++k) {
        if (rkbk[k] >= 0) {
            int b = rkbk[k] & 255;
            int rk = rkbk[k] >> 8;
            rec2[gb[b] + rk] = rc[k];
        }
    }
}

__global__ __launch_bounds__(256) void build_b(const unsigned long long* __restrict__ rec2,
                                               const int* __restrict__ bcursor,
                                               int2* __restrict__ rp2,
                                               unsigned long long* __restrict__ rec,
                                               int n) {
    __shared__ int cnt[256];
    __shared__ int cur[256];
    const int t = threadIdx.x;
    const int b = blockIdx.x;
    const int lo = b * BCAP;
    const int hi = bcursor[b];
    cnt[t] = 0;
    __syncthreads();
    for (int i = lo + t; i < hi; i += 256)
        atomicAdd(&cnt[((unsigned)rec2[i] >> 16) & 255], 1);
    __syncthreads();
    int v = cnt[t];
    cur[t] = v;
    __syncthreads();
    for (int off = 1; off < 256; off <<= 1) {
        int x = (t >= off) ? cur[t - off] : 0;
        __syncthreads();
        cur[t] += x;
        __syncthreads();
    }
    int ex = cur[t] - v;
    int node = b * 256 + t;
    if (node < n) {
        int2 se; se.x = lo + ex; se.y = lo + ex + v;
        rp2[node] = se;
    }
    __syncthreads();
    cur[t] = ex;
    __syncthreads();
    for (int i = lo + t; i < hi; i += 256) {
        unsigned long long r = rec2[i];
        unsigned lo32 = (unsigned)r;
        int ln = (lo32 >> 16) & 255;
        int p = atomicAdd(&cur[ln], 1);
        rec[lo + p] = (r & 0xffffffff00000000ull) | (lo32 & 0xffffu);
    }
}

// ---------------------------------------------------------------------------
// Gather helper: NE edges of one stream (stride 4 records); STRIDE = row
// stride of s in floats. Fully unrolled -> static indexing.
// ---------------------------------------------------------------------------
template <int NE, bool PRED, int STRIDE>
__device__ __forceinline__ void gath(const float* __restrict__ sq,
                                     const unsigned long long* __restrict__ rec,
                                     int e0, int end,
                                     float& ax, float& ay, float& az, float& aw) {
    unsigned long long r[NE];
#pragma unroll
    for (int j = 0; j < NE; ++j)
        r[j] = (!PRED || (e0 + 4 * j < end)) ? rec[e0 + 4 * j] : 0ull;
    float4 v[NE];
#pragma unroll
    for (int j = 0; j < NE; ++j)
        v[j] = *reinterpret_cast<const float4*>(sq + (size_t)(unsigned)(r[j] & 0xffffffffu) * STRIDE);
#pragma unroll
    for (int j = 0; j < NE; ++j) {
        float w = __uint_as_float((unsigned)(r[j] >> 32));
        ax = fmaf(v[j].x, w, ax); ay = fmaf(v[j].y, w, ay);
        az = fmaf(v[j].z, w, az); aw = fmaf(v[j].w, w, aw);
    }
}

// ---------------------------------------------------------------------------
// CSR aggregation v3 (round-10 form, unchanged).
// ---------------------------------------------------------------------------
template <int D, int C, int MODE, bool SMAX>
__global__ __launch_bounds__(256) void agg_fused(const float* __restrict__ s,
                                                 const unsigned long long* __restrict__ rec,
                                                 const int2* __restrict__ rp2,
                                                 const float* __restrict__ Wn,
                                                 const float* __restrict__ res,
                                                 float* __restrict__ out0,
                                                 float* __restrict__ out1,
                                                 float* __restrict__ pred, int n) {
    constexpr int CH = D / 4;  // lanes per edge (col-chunks)
    __shared__ float wl[(MODE == 1 || MODE == 3) ? D * C : 1];
    if (MODE == 1 || MODE == 3) {
        for (int i = threadIdx.x; i < D * C; i += 256) wl[i] = Wn[i];
        __syncthreads();
    }
    constexpr int NPB = 256 / D;
    const int node = blockIdx.x * NPB + threadIdx.x / D;
    const int lane = threadIdx.x % D;
    const int q = lane & (CH - 1);  // col-chunk index
    const int st = lane / CH;       // stream 0..3
    float ax = 0.f, ay = 0.f, az = 0.f, aw = 0.f;
    if (node < n) {
        const float* sq = s + 4 * q;
        int2 se = rp2[node];
        int i = se.x;
        const int end = se.y;
        for (; i + 32 <= end; i += 32)
            gath<8, false, D>(sq, rec, i + st, end, ax, ay, az, aw);
        if (i + 16 <= end) {
            gath<4, false, D>(sq, rec, i + st, end, ax, ay, az, aw);
            i += 16;
        }
        if (i < end)
            gath<4, true, D>(sq, rec, i + st, end, ax, ay, az, aw);
    }
    ax += __shfl_xor(ax, CH, D);  ax += __shfl_xor(ax, 2 * CH, D);
    ay += __shfl_xor(ay, CH, D);  ay += __shfl_xor(ay, 2 * CH, D);
    az += __shfl_xor(az, CH, D);  az += __shfl_xor(az, 2 * CH, D);
    aw += __shfl_xor(aw, CH, D);  aw += __shfl_xor(aw, 2 * CH, D);

    if (MODE == 1) {
        float vx = tanhf(ax), vy = tanhf(ay), vz = tanhf(az), vw = tanhf(aw);
        if (node < n && st == 0) {
            float4 o; o.x = vx; o.y = vy; o.z = vz; o.w = vw;
            *reinterpret_cast<float4*>(out0 + (size_t)node * D + 4 * q) = o;
        }
        if (SMAX) {  // D == 16: softmax over the 16 cols
            float m = fmaxf(fmaxf(vx, vy), fmaxf(vz, vw));
            m = fmaxf(m, __shfl_xor(m, 1, 16));
            m = fmaxf(m, __shfl_xor(m, 2, 16));
            float ex = expf(vx - m), ey = expf(vy - m), ez = expf(vz - m), ew = expf(vw - m);
            float sm = ex + ey + ez + ew;
            sm += __shfl_xor(sm, 1, 16);
            sm += __shfl_xor(sm, 2, 16);
            float inv = 1.f / sm;
            if (node < n && st == 0) {
                float4 o; o.x = ex * inv; o.y = ey * inv; o.z = ez * inv; o.w = ew * inv;
                *reinterpret_cast<float4*>(pred + (size_t)node * 16 + 4 * q) = o;
            }
        }
        const int cc = lane & (C - 1);
        float g = 0.f;
#pragma unroll
        for (int k = 0; k < D; ++k) {
            float comp = ((k & 3) == 0) ? vx : ((k & 3) == 1) ? vy : ((k & 3) == 2) ? vz : vw;
            float vk = __shfl(comp, k >> 2, D);
            g = fmaf(vk, wl[k * C + cc], g);
        }
        if (node < n && lane < C) out1[(size_t)node * C + cc] = g;
    } else if (MODE == 2) {
        if (node < n && st == 0) {
            float4 rv = *reinterpret_cast<const float4*>(res + (size_t)node * D + 4 * q);
            float4 o;
            o.x = tanhf(ax) + rv.x; o.y = tanhf(ay) + rv.y;
            o.z = tanhf(az) + rv.z; o.w = tanhf(aw) + rv.w;
            *reinterpret_cast<float4*>(out0 + (size_t)node * D + 4 * q) = o;
        }
    } else if (MODE == 3) {  // D=16, C=32: out = tanh(accRow @ Wn) + res
        float g0 = 0.f, g1 = 0.f;
#pragma unroll
        for (int k = 0; k < 16; ++k) {
            float comp = ((k & 3) == 0) ? ax : ((k & 3) == 1) ? ay : ((k & 3) == 2) ? az : aw;
            float vk = __shfl(comp, k >> 2, 16);
            g0 = fmaf(vk, wl[k * 32 + lane], g0);
            g1 = fmaf(vk, wl[k * 32 + lane + 16], g1);
        }
        if (node < n) {
            out0[(size_t)node * 32 + lane] = tanhf(g0) + res[(size_t)node * 32 + lane];
            out0[(size_t)node * 32 + lane + 16] = tanhf(g1) + res[(size_t)node * 32 + lane + 16];
        }
    } else {  // MODE 4
        if (node < n && st == 0) {
            float4 o; o.x = ax; o.y = ay; o.z = az; o.w = aw;
            *reinterpret_cast<float4*>(out0 + (size_t)node * D + 4 * q) = o;
        }
    }
}

// ---------------------------------------------------------------------------
// conv6 aggregation, COLUMN-HALF pass: gathers 16 cols (offset HALF*16) of a
// stride-32 array. Distinct-line footprint per pass = 3.2 MB -> fits each
// XCD's 4 MB L2 (unified 6.4 MB needs 51 MB across 8 XCDs -> L3 traffic).
// 16 lanes/node (4 streams x 4 chunks), plain accumulate epilogue.
// ---------------------------------------------------------------------------
template <int HALF>
__global__ __launch_bounds__(256) void agg_c6h(const float* __restrict__ s,
                                               const unsigned long long* __restrict__ rec,
                                               const int2* __restrict__ rp2,
                                               float* __restrict__ out0, int n) {
    const int node = blockIdx.x * 16 + threadIdx.x / 16;
    const int lane = threadIdx.x % 16;
    const int q = lane & 3;   // col-chunk (4 floats)
    const int st = lane >> 2; // stream 0..3
    float ax = 0.f, ay = 0.f, az = 0.f, aw = 0.f;
    if (node < n) {
        const float* sq = s + HALF * 16 + 4 * q;
        int2 se = rp2[node];
        int i = se.x;
        const int end = se.y;
        for (; i + 32 <= end; i += 32)
            gath<8, false, 32>(sq, rec, i + st, end, ax, ay, az, aw);
        if (i + 16 <= end) {
            gath<4, false, 32>(sq, rec, i + st, end, ax, ay, az, aw);
            i += 16;
        }
        if (i < end)
            gath<4, true, 32>(sq, rec, i + st, end, ax, ay, az, aw);
    }
    ax += __shfl_xor(ax, 4, 16);  ax += __shfl_xor(ax, 8, 16);
    ay += __shfl_xor(ay, 4, 16);  ay += __shfl_xor(ay, 8, 16);
    az += __shfl_xor(az, 4, 16);  az += __shfl_xor(az, 8, 16);
    aw += __shfl_xor(aw, 4, 16);  aw += __shfl_xor(aw, 8, 16);
    if (node < n && st == 0) {
        float4 o; o.x = ax; o.y = ay; o.z = az; o.w = aw;
        *reinterpret_cast<float4*>(out0 + (size_t)node * 32 + HALF * 16 + 4 * q) = o;
    }
}

// ---------------------------------------------------------------------------
// GEMM6: QUARTER-split persistent blocks (kept from round 11: ~21 KB LDS ->
// 7 blocks/CU; same staging traffic as half-split).
// ---------------------------------------------------------------------------
#define FT_R 32
__global__ __launch_bounds__(256) void gemm_fout(const float* __restrict__ a,
                                                 const float* __restrict__ W,
                                                 float* __restrict__ out, int n,
                                                 int ntiles) {
    __shared__ float wl[NHID * 128];     // 16 KB (one column quarter)
    __shared__ float aT[NHID][FT_R + 1]; // 4.2 KB
    const int part = blockIdx.x & 3;
    {
        const float4* w4 = reinterpret_cast<const float4*>(W);
        float4* wl4 = reinterpret_cast<float4*>(wl);
#pragma unroll
        for (int i = threadIdx.x; i < NHID * 32; i += 256) {
            int k = i >> 5;
            int j = i & 31;
            wl4[k * 32 + j] = w4[k * 128 + part * 32 + j];
        }
    }
    const int rt = threadIdx.x >> 5;
    const int ct = threadIdx.x & 31;
    const int srr = threadIdx.x >> 3;
    const int sk4 = threadIdx.x & 7;

    for (int tile = blockIdx.x >> 2; tile < ntiles; tile += gridDim.x >> 2) {
        const int r0 = tile * FT_R;
        __syncthreads();
        {
            int r = r0 + srr;
            float4 v;
            if (r < n)
                v = *reinterpret_cast<const float4*>(a + (size_t)r * NHID + sk4 * 4);
            else
                v.x = v.y = v.z = v.w = 0.f;
            aT[sk4 * 4 + 0][srr] = v.x;
            aT[sk4 * 4 + 1][srr] = v.y;
            aT[sk4 * 4 + 2][srr] = v.z;
            aT[sk4 * 4 + 3][srr] = v.w;
        }
        __syncthreads();
        float acc[4][4] = {{0.f}};
#pragma unroll 8
        for (int k = 0; k < NHID; ++k) {
            float4 av = *reinterpret_cast<const float4*>(&aT[k][rt * 4]);
            float4 wv = *reinterpret_cast<const float4*>(&wl[k * 128 + ct * 4]);
            acc[0][0] = fmaf(av.x, wv.x, acc[0][0]);
            acc[0][1] = fmaf(av.x, wv.y, acc[0][1]);
            acc[0][2] = fmaf(av.x, wv.z, acc[0][2]);
            acc[0][3] = fmaf(av.x, wv.w, acc[0][3]);
            acc[1][0] = fmaf(av.y, wv.x, acc[1][0]);
            acc[1][1] = fmaf(av.y, wv.y, acc[1][1]);
            acc[1][2] = fmaf(av.y, wv.z, acc[1][2]);
            acc[1][3] = fmaf(av.y, wv.w, acc[1][3]);
            acc[2][0] = fmaf(av.z, wv.x, acc[2][0]);
            acc[2][1] = fmaf(av.z, wv.y, acc[2][1]);
            acc[2][2] = fmaf(av.z, wv.z, acc[2][2]);
            acc[2][3] = fmaf(av.z, wv.w, acc[2][3]);
            acc[3][0] = fmaf(av.w, wv.x, acc[3][0]);
            acc[3][1] = fmaf(av.w, wv.y, acc[3][1]);
            acc[3][2] = fmaf(av.w, wv.z, acc[3][2]);
            acc[3][3] = fmaf(av.w, wv.w, acc[3][3]);
        }
#pragma unroll
        for (int i = 0; i < 4; ++i) {
            int r = r0 + rt * 4 + i;
            if (r < n) {
                float4 o;
                o.x = 1.f / (1.f + expf(-acc[i][0]));
                o.y = 1.f / (1.f + expf(-acc[i][1]));
                o.z = 1.f / (1.f + expf(-acc[i][2]));
                o.w = 1.f / (1.f + expf(-acc[i][3]));
                *reinterpret_cast<float4*>(out + (size_t)r * FIN + part * 128 + ct * 4) = o;
            }
        }
    }
}

extern "C" void kernel_launch(void* const* d_in, const int* in_sizes, int n_in,
                              void* d_out, int out_size, void* d_ws, size_t ws_size,
                              hipStream_t stream) {
    const float* feat = (const float*)d_in[0];
    const int* esrc = (const int*)d_in[1];
    const int* edst = (const int*)d_in[2];
    const float* ewt = (const float*)d_in[3];
    const float* W1 = (const float*)d_in[4];
    const float* W2 = (const float*)d_in[5];
    const float* W3 = (const float*)d_in[6];
    const float* W4 = (const float*)d_in[7];
    const float* W5 = (const float*)d_in[8];
    const float* W6 = (const float*)d_in[9];
    const int n = in_sizes[0] / FIN;
    const int e = in_sizes[1];
    const int nb = (n + 255) >> 8;  // 196 buckets of 256 nodes

    float* out = (float*)d_out;
    float* recon = out;                   // [n,512]
    float* zout = out + (size_t)n * FIN;  // [n,16]
    float* pred = zout + (size_t)n * 16;  // [n,16]

    // Workspace: rec | rec2 | rp2 | bcursor | float buffers.
    char* wsb = (char*)d_ws;
    const size_t captot = (size_t)nb * BCAP;
    unsigned long long* rec = (unsigned long long*)wsb;   // captot * 8B
    unsigned long long* rec2 = rec + captot;              // captot * 8B
    int2* rp2 = (int2*)(rec2 + captot);                   // n * 8B
    int* bcursor = (int*)(rp2 + n);                       // nb
    size_t ioff = (size_t)((bcursor + nb) - (int*)wsb);
    ioff = (ioff + 3) & ~(size_t)3;
    float* S_a = (float*)wsb + ioff;    // n*32
    float* S_b = S_a + (size_t)n * 32;  // n*32
    float* X1 = S_b + (size_t)n * 32;   // n*32 (x1)
    float* X2 = X1 + (size_t)n * 32;    // n*16 (x2)
    float* G1 = X2 + (size_t)n * 16;    // n*32 (K-split partial)

    const int geb = (e + 4095) / 4096;
    const int gn32 = (n + 7) / 8;
    const int gn16 = (n + 15) / 16;
    const int ntile1 = (n + BR - 1) / BR;
    const int ntiles6 = (n + FT_R - 1) / FT_R;

    // ---- CSR build ----
    binit<<<1, 256, 0, stream>>>(bcursor, nb);
    build_a<<<geb, 256, 0, stream>>>(esrc, edst, ewt, bcursor, rec2, e, nb);
    build_b<<<nb, 256, 0, stream>>>(rec2, bcursor, rp2, rec, n);

    // conv1: s1 = feat@W1 (K-split partials -> S_a, G1; add2 -> S_a)
    gemm_fin<<<2 * ntile1, 256, 0, stream>>>(feat, W1, S_a, G1, n, ntile1);
    add2<<<(n * 32 / 4 + 255) / 256, 256, 0, stream>>>(S_a, G1, n * 32 / 4);
    // x1 = tanh(A s1) -> X1 ; s2 = x1@W2 -> S_b
    agg_fused<32, 16, 1, false><<<gn32, 256, 0, stream>>>(S_a, rec, rp2, W2, nullptr, X1, S_b, nullptr, n);
    // conv2: x2 = tanh(A s2) -> X2 ; s3 = x2@W3 -> S_a
    agg_fused<16, 16, 1, false><<<gn16, 256, 0, stream>>>(S_b, rec, rp2, W3, nullptr, X2, S_a, nullptr, n);
    // conv3: z = tanh(A s3) -> zout ; pred = softmax(z) ; s4 = z@W4 -> S_b
    agg_fused<16, 16, 1, true><<<gn16, 256, 0, stream>>>(S_a, rec, rp2, W4, nullptr, zout, S_b, pred, n);
    // conv4: z2 = tanh(A s4) + x2 -> S_a
    agg_fused<16, 16, 2, false><<<gn16, 256, 0, stream>>>(S_b, rec, rp2, nullptr, X2, S_a, nullptr, nullptr, n);
    // conv5: z1 = tanh((A z2)@W5) + x1 -> S_b
    agg_fused<16, 32, 3, false><<<gn16, 256, 0, stream>>>(S_a, rec, rp2, W5, X1, S_b, nullptr, nullptr, n);
    // conv6: A z1 -> S_a, split into two L2-resident column-half passes
    agg_c6h<0><<<gn16, 256, 0, stream>>>(S_b, rec, rp2, S_a, n);
    agg_c6h<1><<<gn16, 256, 0, stream>>>(S_b, rec, rp2, S_a, n);
    // recon = sigmoid(S_a @ W6)
    gemm_fout<<<2048, 256, 0, stream>>>(S_a, W6, recon, n, ntiles6);
}

// Round 15
// 293.235 us; speedup vs baseline: 1.1041x; 1.1041x over previous
//
#include <hip/hip_runtime.h>
#include <hip/hip_bf16.h>
#include <math.h>

#define FIN 512
#define NHID 32
#define LAT 16
#define BCAP 16384  // records per 256-node bucket (mean 8192, sigma ~90)

typedef float v4f __attribute__((ext_vector_type(4)));  // for nontemporal stores

// ---------------------------------------------------------------------------
// GEMM1: [n,512] @ [512,32] -> [n,32]. K-split x2, XOR-swizzled xT
// (round-10 form — best measured).
// ---------------------------------------------------------------------------
#define BR 128
#define KC 64
__global__ __launch_bounds__(256) void gemm_fin(const float* __restrict__ feat,
                                                const float* __restrict__ W,
                                                float* __restrict__ out0,
                                                float* __restrict__ out1,
                                                int n, int ntile) {
    __shared__ float xT[KC][BR];    // 32 KB, swizzled
    __shared__ float Wc[KC][NHID];  // 8 KB
    const int tid = threadIdx.x;
    const int tile = blockIdx.x % ntile;
    const int khalf = blockIdx.x / ntile;
    const int r0 = tile * BR;
    const int k0 = khalf * 256;
    float* __restrict__ out = khalf ? out1 : out0;
    const int rt = tid >> 3;
    const int ct = tid & 7;
    const int srow = tid >> 4;
    const int sc4 = tid & 15;
    float acc[4][4] = {{0.f}};

    for (int kc = 0; kc < 256; kc += KC) {
        {
            const float4* wg = reinterpret_cast<const float4*>(W + (k0 + kc) * NHID);
            float4* wl = reinterpret_cast<float4*>(&Wc[0][0]);
            wl[tid] = wg[tid];
            wl[tid + 256] = wg[tid + 256];
        }
#pragma unroll
        for (int i = 0; i < 8; ++i) {
            int rr = srow + 16 * i;
            int r = r0 + rr;
            float4 v;
            if (r < n)
                v = *reinterpret_cast<const float4*>(feat + (size_t)r * FIN + k0 + kc + sc4 * 4);
            else
                v.x = v.y = v.z = v.w = 0.f;
            int gs = ((rr >> 2) ^ (sc4 & 7)) * 4 + (rr & 3);
            xT[sc4 * 4 + 0][gs] = v.x;
            xT[sc4 * 4 + 1][gs] = v.y;
            xT[sc4 * 4 + 2][gs] = v.z;
            xT[sc4 * 4 + 3][gs] = v.w;
        }
        __syncthreads();
#pragma unroll 4
        for (int k = 0; k < KC; ++k) {
            int sw = (rt ^ ((k >> 2) & 7)) * 4;
            float4 xv = *reinterpret_cast<const float4*>(&xT[k][sw]);
            float4 wv = *reinterpret_cast<const float4*>(&Wc[k][ct * 4]);
            acc[0][0] = fmaf(xv.x, wv.x, acc[0][0]);
            acc[0][1] = fmaf(xv.x, wv.y, acc[0][1]);
            acc[0][2] = fmaf(xv.x, wv.z, acc[0][2]);
            acc[0][3] = fmaf(xv.x, wv.w, acc[0][3]);
            acc[1][0] = fmaf(xv.y, wv.x, acc[1][0]);
            acc[1][1] = fmaf(xv.y, wv.y, acc[1][1]);
            acc[1][2] = fmaf(xv.y, wv.z, acc[1][2]);
            acc[1][3] = fmaf(xv.y, wv.w, acc[1][3]);
            acc[2][0] = fmaf(xv.z, wv.x, acc[2][0]);
            acc[2][1] = fmaf(xv.z, wv.y, acc[2][1]);
            acc[2][2] = fmaf(xv.z, wv.z, acc[2][2]);
            acc[2][3] = fmaf(xv.z, wv.w, acc[2][3]);
            acc[3][0] = fmaf(xv.w, wv.x, acc[3][0]);
            acc[3][1] = fmaf(xv.w, wv.y, acc[3][1]);
            acc[3][2] = fmaf(xv.w, wv.z, acc[3][2]);
            acc[3][3] = fmaf(xv.w, wv.w, acc[3][3]);
        }
        __syncthreads();
    }
#pragma unroll
    for (int i = 0; i < 4; ++i) {
        int r = r0 + rt * 4 + i;
        if (r < n) {
            float4 o;
            o.x = acc[i][0]; o.y = acc[i][1]; o.z = acc[i][2]; o.w = acc[i][3];
            *reinterpret_cast<float4*>(out + (size_t)r * NHID + ct * 4) = o;
        }
    }
}

// a += b (float4), for the K-split reduction.
__global__ __launch_bounds__(256) void add2(float* __restrict__ a,
                                            const float* __restrict__ b, int n4) {
    int i = blockIdx.x * 256 + threadIdx.x;
    if (i < n4) {
        float4 va = reinterpret_cast<float4*>(a)[i];
        float4 vb = reinterpret_cast<const float4*>(b)[i];
        va.x += vb.x; va.y += vb.y; va.z += vb.z; va.w += vb.w;
        reinterpret_cast<float4*>(a)[i] = va;
    }
}

// ---------------------------------------------------------------------------
// CSR build, fixed-capacity buckets (round-10 form).
// ---------------------------------------------------------------------------
__global__ __launch_bounds__(256) void binit(int* __restrict__ bcursor, int nb) {
    int t = threadIdx.x;
    if (t < nb) bcursor[t] = t * BCAP;
}

__global__ __launch_bounds__(256) void build_a(const int* __restrict__ src,
                                               const int* __restrict__ dst,
                                               const float* __restrict__ w,
                                               int* __restrict__ bcursor,
                                               unsigned long long* __restrict__ rec2,
                                               int e, int nb) {
    __shared__ int cnt[256];
    __shared__ int gb[256];
    const int tid = threadIdx.x;
    const int i0 = blockIdx.x * 4096;
    cnt[tid] = 0;
    __syncthreads();
    unsigned long long rc[16];
    int rkbk[16];
#pragma unroll
    for (int k = 0; k < 16; ++k) {
        int j = i0 + k * 256 + tid;
        rkbk[k] = -1;
        if (j < e) {
            int d = dst[j];
            int b = d >> 8;
            int rk = atomicAdd(&cnt[b], 1);
            rkbk[k] = (rk << 8) | b;
            rc[k] = ((unsigned long long)__float_as_uint(w[j]) << 32) |
                    ((unsigned)d << 16) | (unsigned)src[j];
        }
    }
    __syncthreads();
    if (tid < nb && cnt[tid] > 0) gb[tid] = atomicAdd(&bcursor[tid], cnt[tid]);
    __syncthreads();
#pragma unroll
    for (int k = 0; k < 16; ++k) {
        if (rkbk[k] >= 0) {
            int b = rkbk[k] & 255;
            int rk = rkbk[k] >> 8;
            rec2[gb[b] + rk] = rc[k];
        }
    }
}

__global__ __launch_bounds__(256) void build_b(const unsigned long long* __restrict__ rec2,
                                               const int* __restrict__ bcursor,
                                               int2* __restrict__ rp2,
                                               unsigned long long* __restrict__ rec,
                                               int n) {
    __shared__ int cnt[256];
    __shared__ int cur[256];
    const int t = threadIdx.x;
    const int b = blockIdx.x;
    const int lo = b * BCAP;
    const int hi = bcursor[b];
    cnt[t] = 0;
    __syncthreads();
    for (int i = lo + t; i < hi; i += 256)
        atomicAdd(&cnt[((unsigned)rec2[i] >> 16) & 255], 1);
    __syncthreads();
    int v = cnt[t];
    cur[t] = v;
    __syncthreads();
    for (int off = 1; off < 256; off <<= 1) {
        int x = (t >= off) ? cur[t - off] : 0;
        __syncthreads();
        cur[t] += x;
        __syncthreads();
    }
    int ex = cur[t] - v;
    int node = b * 256 + t;
    if (node < n) {
        int2 se; se.x = lo + ex; se.y = lo + ex + v;
        rp2[node] = se;
    }
    __syncthreads();
    cur[t] = ex;
    __syncthreads();
    for (int i = lo + t; i < hi; i += 256) {
        unsigned long long r = rec2[i];
        unsigned lo32 = (unsigned)r;
        int ln = (lo32 >> 16) & 255;
        int p = atomicAdd(&cur[ln], 1);
        rec[lo + p] = (r & 0xffffffff00000000ull) | (lo32 & 0xffffu);
    }
}

// ---------------------------------------------------------------------------
// Gather helper (round-10 form).
// ---------------------------------------------------------------------------
template <int NE, bool PRED, int D>
__device__ __forceinline__ void gath(const float* __restrict__ sq,
                                     const unsigned long long* __restrict__ rec,
                                     int e0, int end,
                                     float& ax, float& ay, float& az, float& aw) {
    unsigned long long r[NE];
#pragma unroll
    for (int j = 0; j < NE; ++j)
        r[j] = (!PRED || (e0 + 4 * j < end)) ? rec[e0 + 4 * j] : 0ull;
    float4 v[NE];
#pragma unroll
    for (int j = 0; j < NE; ++j)
        v[j] = *reinterpret_cast<const float4*>(sq + (size_t)(unsigned)(r[j] & 0xffffffffu) * D);
#pragma unroll
    for (int j = 0; j < NE; ++j) {
        float w = __uint_as_float((unsigned)(r[j] >> 32));
        ax = fmaf(v[j].x, w, ax); ay = fmaf(v[j].y, w, ay);
        az = fmaf(v[j].z, w, az); aw = fmaf(v[j].w, w, aw);
    }
}

// ---------------------------------------------------------------------------
// CSR aggregation v3 (round-10 form, unchanged).
// ---------------------------------------------------------------------------
template <int D, int C, int MODE, bool SMAX>
__global__ __launch_bounds__(256) void agg_fused(const float* __restrict__ s,
                                                 const unsigned long long* __restrict__ rec,
                                                 const int2* __restrict__ rp2,
                                                 const float* __restrict__ Wn,
                                                 const float* __restrict__ res,
                                                 float* __restrict__ out0,
                                                 float* __restrict__ out1,
                                                 float* __restrict__ pred, int n) {
    constexpr int CH = D / 4;  // lanes per edge (col-chunks)
    __shared__ float wl[(MODE == 1 || MODE == 3) ? D * C : 1];
    if (MODE == 1 || MODE == 3) {
        for (int i = threadIdx.x; i < D * C; i += 256) wl[i] = Wn[i];
        __syncthreads();
    }
    constexpr int NPB = 256 / D;
    const int node = blockIdx.x * NPB + threadIdx.x / D;
    const int lane = threadIdx.x % D;
    const int q = lane & (CH - 1);  // col-chunk index
    const int st = lane / CH;       // stream 0..3
    float ax = 0.f, ay = 0.f, az = 0.f, aw = 0.f;
    if (node < n) {
        const float* sq = s + 4 * q;
        int2 se = rp2[node];
        int i = se.x;
        const int end = se.y;
        for (; i + 32 <= end; i += 32)
            gath<8, false, D>(sq, rec, i + st, end, ax, ay, az, aw);
        if (i + 16 <= end) {
            gath<4, false, D>(sq, rec, i + st, end, ax, ay, az, aw);
            i += 16;
        }
        if (i < end)
            gath<4, true, D>(sq, rec, i + st, end, ax, ay, az, aw);
    }
    ax += __shfl_xor(ax, CH, D);  ax += __shfl_xor(ax, 2 * CH, D);
    ay += __shfl_xor(ay, CH, D);  ay += __shfl_xor(ay, 2 * CH, D);
    az += __shfl_xor(az, CH, D);  az += __shfl_xor(az, 2 * CH, D);
    aw += __shfl_xor(aw, CH, D);  aw += __shfl_xor(aw, 2 * CH, D);

    if (MODE == 1) {
        float vx = tanhf(ax), vy = tanhf(ay), vz = tanhf(az), vw = tanhf(aw);
        if (node < n && st == 0) {
            float4 o; o.x = vx; o.y = vy; o.z = vz; o.w = vw;
            *reinterpret_cast<float4*>(out0 + (size_t)node * D + 4 * q) = o;
        }
        if (SMAX) {  // D == 16: softmax over the 16 cols
            float m = fmaxf(fmaxf(vx, vy), fmaxf(vz, vw));
            m = fmaxf(m, __shfl_xor(m, 1, 16));
            m = fmaxf(m, __shfl_xor(m, 2, 16));
            float ex = expf(vx - m), ey = expf(vy - m), ez = expf(vz - m), ew = expf(vw - m);
            float sm = ex + ey + ez + ew;
            sm += __shfl_xor(sm, 1, 16);
            sm += __shfl_xor(sm, 2, 16);
            float inv = 1.f / sm;
            if (node < n && st == 0) {
                float4 o; o.x = ex * inv; o.y = ey * inv; o.z = ez * inv; o.w = ew * inv;
                *reinterpret_cast<float4*>(pred + (size_t)node * 16 + 4 * q) = o;
            }
        }
        const int cc = lane & (C - 1);
        float g = 0.f;
#pragma unroll
        for (int k = 0; k < D; ++k) {
            float comp = ((k & 3) == 0) ? vx : ((k & 3) == 1) ? vy : ((k & 3) == 2) ? vz : vw;
            float vk = __shfl(comp, k >> 2, D);
            g = fmaf(vk, wl[k * C + cc], g);
        }
        if (node < n && lane < C) out1[(size_t)node * C + cc] = g;
    } else if (MODE == 2) {
        if (node < n && st == 0) {
            float4 rv = *reinterpret_cast<const float4*>(res + (size_t)node * D + 4 * q);
            float4 o;
            o.x = tanhf(ax) + rv.x; o.y = tanhf(ay) + rv.y;
            o.z = tanhf(az) + rv.z; o.w = tanhf(aw) + rv.w;
            *reinterpret_cast<float4*>(out0 + (size_t)node * D + 4 * q) = o;
        }
    } else if (MODE == 3) {  // D=16, C=32: out = tanh(accRow @ Wn) + res
        float g0 = 0.f, g1 = 0.f;
#pragma unroll
        for (int k = 0; k < 16; ++k) {
            float comp = ((k & 3) == 0) ? ax : ((k & 3) == 1) ? ay : ((k & 3) == 2) ? az : aw;
            float vk = __shfl(comp, k >> 2, 16);
            g0 = fmaf(vk, wl[k * 32 + lane], g0);
            g1 = fmaf(vk, wl[k * 32 + lane + 16], g1);
        }
        if (node < n) {
            out0[(size_t)node * 32 + lane] = tanhf(g0) + res[(size_t)node * 32 + lane];
            out0[(size_t)node * 32 + lane + 16] = tanhf(g1) + res[(size_t)node * 32 + lane + 16];
        }
    } else {  // MODE 4
        if (node < n && st == 0) {
            float4 o; o.x = ax; o.y = ay; o.z = az; o.w = aw;
            *reinterpret_cast<float4*>(out0 + (size_t)node * D + 4 * q) = o;
        }
    }
}

// ---------------------------------------------------------------------------
// GEMM6: HALF-split persistent blocks (round-10 form) + NON-TEMPORAL stores
// for recon (100 MB written once, never re-read -> keep it out of L2 so the
// reused a-array and W6 stay resident). Uses ext_vector_type for the builtin.
// ---------------------------------------------------------------------------
#define FT_R 32
__global__ __launch_bounds__(256) void gemm_fout(const float* __restrict__ a,
                                                 const float* __restrict__ W,
                                                 float* __restrict__ out, int n,
                                                 int ntiles) {
    __shared__ float wl[NHID * 256];     // 32 KB (one column half)
    __shared__ float aT[NHID][FT_R + 1]; // 4.2 KB
    const int part = blockIdx.x & 1;
    {
        const float4* w4 = reinterpret_cast<const float4*>(W);
        float4* wl4 = reinterpret_cast<float4*>(wl);
#pragma unroll
        for (int i = threadIdx.x; i < NHID * 64; i += 256) {
            int k = i >> 6;
            int j = i & 63;
            wl4[k * 64 + j] = w4[k * 128 + part * 64 + j];
        }
    }
    const int rt = threadIdx.x >> 5;
    const int ct = threadIdx.x & 31;
    const int srr = threadIdx.x >> 3;
    const int sk4 = threadIdx.x & 7;

    for (int tile = blockIdx.x >> 1; tile < ntiles; tile += gridDim.x >> 1) {
        const int r0 = tile * FT_R;
        __syncthreads();
        {
            int r = r0 + srr;
            float4 v;
            if (r < n)
                v = *reinterpret_cast<const float4*>(a + (size_t)r * NHID + sk4 * 4);
            else
                v.x = v.y = v.z = v.w = 0.f;
            aT[sk4 * 4 + 0][srr] = v.x;
            aT[sk4 * 4 + 1][srr] = v.y;
            aT[sk4 * 4 + 2][srr] = v.z;
            aT[sk4 * 4 + 3][srr] = v.w;
        }
        __syncthreads();
#pragma unroll
        for (int cc = 0; cc < 2; ++cc) {
            float acc[4][4] = {{0.f}};
#pragma unroll 8
            for (int k = 0; k < NHID; ++k) {
                float4 av = *reinterpret_cast<const float4*>(&aT[k][rt * 4]);
                float4 wv = *reinterpret_cast<const float4*>(&wl[k * 256 + cc * 128 + ct * 4]);
                acc[0][0] = fmaf(av.x, wv.x, acc[0][0]);
                acc[0][1] = fmaf(av.x, wv.y, acc[0][1]);
                acc[0][2] = fmaf(av.x, wv.z, acc[0][2]);
                acc[0][3] = fmaf(av.x, wv.w, acc[0][3]);
                acc[1][0] = fmaf(av.y, wv.x, acc[1][0]);
                acc[1][1] = fmaf(av.y, wv.y, acc[1][1]);
                acc[1][2] = fmaf(av.y, wv.z, acc[1][2]);
                acc[1][3] = fmaf(av.y, wv.w, acc[1][3]);
                acc[2][0] = fmaf(av.z, wv.x, acc[2][0]);
                acc[2][1] = fmaf(av.z, wv.y, acc[2][1]);
                acc[2][2] = fmaf(av.z, wv.z, acc[2][2]);
                acc[2][3] = fmaf(av.z, wv.w, acc[2][3]);
                acc[3][0] = fmaf(av.w, wv.x, acc[3][0]);
                acc[3][1] = fmaf(av.w, wv.y, acc[3][1]);
                acc[3][2] = fmaf(av.w, wv.z, acc[3][2]);
                acc[3][3] = fmaf(av.w, wv.w, acc[3][3]);
            }
#pragma unroll
            for (int i = 0; i < 4; ++i) {
                int r = r0 + rt * 4 + i;
                if (r < n) {
                    v4f o;
                    o.x = 1.f / (1.f + expf(-acc[i][0]));
                    o.y = 1.f / (1.f + expf(-acc[i][1]));
                    o.z = 1.f / (1.f + expf(-acc[i][2]));
                    o.w = 1.f / (1.f + expf(-acc[i][3]));
                    __builtin_nontemporal_store(o, reinterpret_cast<v4f*>(
                        out + (size_t)r * FIN + part * 256 + cc * 128 + ct * 4));
                }
            }
        }
    }
}

extern "C" void kernel_launch(void* const* d_in, const int* in_sizes, int n_in,
                              void* d_out, int out_size, void* d_ws, size_t ws_size,
                              hipStream_t stream) {
    const float* feat = (const float*)d_in[0];
    const int* esrc = (const int*)d_in[1];
    const int* edst = (const int*)d_in[2];
    const float* ewt = (const float*)d_in[3];
    const float* W1 = (const float*)d_in[4];
    const float* W2 = (const float*)d_in[5];
    const float* W3 = (const float*)d_in[6];
    const float* W4 = (const float*)d_in[7];
    const float* W5 = (const float*)d_in[8];
    const float* W6 = (const float*)d_in[9];
    const int n = in_sizes[0] / FIN;
    const int e = in_sizes[1];
    const int nb = (n + 255) >> 8;  // 196 buckets of 256 nodes

    float* out = (float*)d_out;
    float* recon = out;                   // [n,512]
    float* zout = out + (size_t)n * FIN;  // [n,16]
    float* pred = zout + (size_t)n * 16;  // [n,16]

    // Workspace: rec | rec2 | rp2 | bcursor | float buffers.
    char* wsb = (char*)d_ws;
    const size_t captot = (size_t)nb * BCAP;
    unsigned long long* rec = (unsigned long long*)wsb;   // captot * 8B
    unsigned long long* rec2 = rec + captot;              // captot * 8B
    int2* rp2 = (int2*)(rec2 + captot);                   // n * 8B
    int* bcursor = (int*)(rp2 + n);                       // nb
    size_t ioff = (size_t)((bcursor + nb) - (int*)wsb);
    ioff = (ioff + 3) & ~(size_t)3;
    float* S_a = (float*)wsb + ioff;    // n*32
    float* S_b = S_a + (size_t)n * 32;  // n*32
    float* X1 = S_b + (size_t)n * 32;   // n*32 (x1)
    float* X2 = X1 + (size_t)n * 32;    // n*16 (x2)
    float* G1 = X2 + (size_t)n * 16;    // n*32 (K-split partial)

    const int geb = (e + 4095) / 4096;
    const int gn32 = (n + 7) / 8;
    const int gn16 = (n + 15) / 16;
    const int ntile1 = (n + BR - 1) / BR;
    const int ntiles6 = (n + FT_R - 1) / FT_R;

    // ---- CSR build ----
    binit<<<1, 256, 0, stream>>>(bcursor, nb);
    build_a<<<geb, 256, 0, stream>>>(esrc, edst, ewt, bcursor, rec2, e, nb);
    build_b<<<nb, 256, 0, stream>>>(rec2, bcursor, rp2, rec, n);

    // conv1: s1 = feat@W1 (K-split partials -> S_a, G1; add2 -> S_a)
    gemm_fin<<<2 * ntile1, 256, 0, stream>>>(feat, W1, S_a, G1, n, ntile1);
    add2<<<(n * 32 / 4 + 255) / 256, 256, 0, stream>>>(S_a, G1, n * 32 / 4);
    // x1 = tanh(A s1) -> X1 ; s2 = x1@W2 -> S_b
    agg_fused<32, 16, 1, false><<<gn32, 256, 0, stream>>>(S_a, rec, rp2, W2, nullptr, X1, S_b, nullptr, n);
    // conv2: x2 = tanh(A s2) -> X2 ; s3 = x2@W3 -> S_a
    agg_fused<16, 16, 1, false><<<gn16, 256, 0, stream>>>(S_b, rec, rp2, W3, nullptr, X2, S_a, nullptr, n);
    // conv3: z = tanh(A s3) -> zout ; pred = softmax(z) ; s4 = z@W4 -> S_b
    agg_fused<16, 16, 1, true><<<gn16, 256, 0, stream>>>(S_a, rec, rp2, W4, nullptr, zout, S_b, pred, n);
    // conv4: z2 = tanh(A s4) + x2 -> S_a
    agg_fused<16, 16, 2, false><<<gn16, 256, 0, stream>>>(S_b, rec, rp2, nullptr, X2, S_a, nullptr, nullptr, n);
    // conv5: z1 = tanh((A z2)@W5) + x1 -> S_b
    agg_fused<16, 32, 3, false><<<gn16, 256, 0, stream>>>(S_a, rec, rp2, W5, X1, S_b, nullptr, nullptr, n);
    // conv6: A z1 -> S_a (single D=32 pass — the split variant measured worse)
    agg_fused<32, 32, 4, false><<<gn32, 256, 0, stream>>>(S_b, rec, rp2, nullptr, nullptr, S_a, nullptr, nullptr, n);
    // recon = sigmoid(S_a @ W6)
    gemm_fout<<<1024, 256, 0, stream>>>(S_a, W6, recon, n, ntiles6);
}